// Round 7
// baseline (349.950 us; speedup 1.0000x reference)
//
#include <hip/hip_runtime.h>

typedef unsigned short u16;
typedef unsigned int u32;
typedef unsigned long long u64;
typedef float f32x4 __attribute__((ext_vector_type(4)));
typedef __bf16 bf16x8 __attribute__((ext_vector_type(8)));
typedef __bf16 bf16x4 __attribute__((ext_vector_type(4)));
typedef u16 u16x8 __attribute__((ext_vector_type(8)));

#define DEV __device__ __forceinline__

// ---- constants for this problem ----
// B=4, T=1296 (36x36 patches), E=768, H=12, HD=64, M = B*T = 5184
// patch K = C_IN*P*P = 3*16*16 = 768

DEV u16 f2bf(float f) {
    union { float f; u32 u; } un; un.f = f;
    u32 u = un.u;
    return (u16)((u + 0x7fffu + ((u >> 16) & 1u)) >> 16);
}

DEV void gll16(const u16* src, u16* dst) {
    auto g = (const __attribute__((address_space(1))) u32*)(src);
    auto s = (__attribute__((address_space(3))) u32*)(dst);
    __builtin_amdgcn_global_load_lds(g, s, 16, 0, 0);
}

// ---------------- weight convert / transpose ----------------
__global__ void convcvt_k(const float* __restrict__ src, u16* __restrict__ dst) {
    int i = blockIdx.x * 256 + threadIdx.x;          // one float4 per thread
    f32x4 v = ((const f32x4*)src)[i];
    union { u16 q[4]; u64 ll; } un;
    #pragma unroll
    for (int j = 0; j < 4; ++j) un.q[j] = f2bf(v[j]);
    ((u64*)dst)[i] = un.ll;
}

// src: f32 [K][N] row-major; dst: bf16 [N][K]
__global__ void wtrans_k(const float* __restrict__ src, u16* __restrict__ dst, int K, int N) {
    __shared__ float tile[32][33];
    int n0 = blockIdx.x * 32, k0 = blockIdx.y * 32;
    int tx = threadIdx.x & 31, ty = threadIdx.x >> 5;   // 32 x 8
    #pragma unroll
    for (int i = 0; i < 32; i += 8)
        tile[ty + i][tx] = src[(size_t)(k0 + ty + i) * N + n0 + tx];
    __syncthreads();
    #pragma unroll
    for (int i = 0; i < 32; i += 8)
        dst[(size_t)(n0 + ty + i) * K + k0 + tx] = f2bf(tile[tx][ty + i]);
}

// ---------------- patch gather: x (B,3,576,576) -> A [5184][768] bf16 ----------------
__global__ void patch_k(const float* __restrict__ x, u16* __restrict__ out) {
    int idx = blockIdx.x * 256 + threadIdx.x;   // [b][c][i][p][j], j innermost
    int j = idx % 36; int r1 = idx / 36;
    int p = r1 % 16;  int r2 = r1 / 16;
    int i = r2 % 36;  int r3 = r2 / 36;
    int c = r3 % 3;   int b = r3 / 3;
    const f32x4* src = (const f32x4*)(x + (size_t)((b * 3 + c) * 576 + i * 16 + p) * 576 + j * 16);
    u16x8 lo, hi;
    #pragma unroll
    for (int k = 0; k < 2; ++k) {
        f32x4 v = src[k];
        #pragma unroll
        for (int e = 0; e < 4; ++e) lo[k * 4 + e] = f2bf(v[e]);
    }
    #pragma unroll
    for (int k = 0; k < 2; ++k) {
        f32x4 v = src[2 + k];
        #pragma unroll
        for (int e = 0; e < 4; ++e) hi[k * 4 + e] = f2bf(v[e]);
    }
    u16* dst = out + (size_t)(b * 1296 + i * 36 + j) * 768 + c * 256 + p * 16;
    *(u16x8*)dst = lo;
    *(u16x8*)(dst + 8) = hi;
}

// ---------------- LayerNorm: f32 [5184][768] -> bf16 [5184][768] ----------------
__global__ __launch_bounds__(256) void ln_k(const float* __restrict__ x, const float* __restrict__ g,
                                            const float* __restrict__ bta, u16* __restrict__ out) {
    int row = blockIdx.x * 4 + (threadIdx.x >> 6);
    int l = threadIdx.x & 63;
    const float* xr = x + (size_t)row * 768;
    float v[12]; float s = 0.f, s2 = 0.f;
    #pragma unroll
    for (int i = 0; i < 12; ++i) { v[i] = xr[l + 64 * i]; s += v[i]; s2 += v[i] * v[i]; }
    #pragma unroll
    for (int off = 32; off; off >>= 1) { s += __shfl_xor(s, off); s2 += __shfl_xor(s2, off); }
    float mu = s * (1.f / 768.f);
    float var = s2 * (1.f / 768.f) - mu * mu;
    float rs = rsqrtf(var + 1e-5f);
    u16* orow = out + (size_t)row * 768;
    #pragma unroll
    for (int i = 0; i < 12; ++i) {
        int c = l + 64 * i;
        orow[c] = f2bf((v[i] - mu) * rs * g[c] + bta[c]);
    }
}

// ---------------- V transpose: qkv[.][1536+h*64+d] -> vt[bh][d][t] (t padded to 1344) ----------------
__global__ void vtrans_k(const u16* __restrict__ qkv, u16* __restrict__ vt) {
    __shared__ u16 tile[32][33];
    int bh = blockIdx.z; int b = bh / 12, h = bh % 12;
    int t0 = blockIdx.x * 32, d0 = blockIdx.y * 32;
    int tx = threadIdx.x & 31, ty = threadIdx.x >> 5;
    #pragma unroll
    for (int i = 0; i < 32; i += 8) {
        int t = t0 + ty + i; int tc = min(t, 1295);
        tile[ty + i][tx] = qkv[(size_t)(b * 1296 + tc) * 2304 + 1536 + h * 64 + d0 + tx];
    }
    __syncthreads();
    #pragma unroll
    for (int i = 0; i < 32; i += 8) {
        int d = d0 + ty + i; int t = t0 + tx;
        if (t < 1296) vt[(size_t)(bh * 64 + d) * 1344 + t] = tile[tx][ty + i];
    }
}

// ---------------- GEMM v3: C[M][N] = A[M][K] @ Bt[N][K]^T (+epilogue) ----------------
// BK=64, BN=64, piece^(row&7) swizzle (conflict-free), XCD-chunked bijective decode,
// TRIPLE-buffered LDS with 2-deep prefetch and COUNTED vmcnt across raw s_barrier
// (T4: prefetch batches stay in flight across barriers; never drain to 0 mid-loop).
// Steady state: at barrier, 12 loads (batches kt+1, kt+2) in flight, batch kt landed.
// EPI: 0 = +bias, f32 store        (patch embed -> tok)
//      1 = bf16 store, no bias     (qkv)
//      2 = +bias, relu, bf16 store (mlp1 -> a1)
//      3 = +bias, +resid, f32 store(proj -> tok)
//      4 = +bias, +resid, f32 store TRANSPOSED to (B,E,T)   (mlp2 -> d_out)
template <int BN, int EPI>
__global__ __launch_bounds__(256) void gemm_k(const u16* __restrict__ A, const u16* __restrict__ Bt,
                                              const float* __restrict__ bias, const float* __restrict__ resid,
                                              void* __restrict__ Cout, int K, int ldc, int nbx) {
    static_assert(BN == 64, "pipeline constants assume BN=64 (6 loads/thread/stage)");
    constexpr int M = 5184;
    constexpr int NF = BN / 32;
    // 3 buffers x (128 A-rows + BN B-rows) x 64 u16 (128B rows)
    __shared__ __align__(16) u16 lds[3][(128 + BN) * 64];
    const int tid = threadIdx.x;
    const int l = tid & 63, w = tid >> 6;
    const int lr = l & 15, lq = l >> 4;
    const int wm = w >> 1, wn = w & 1;

    // bijective XCD-chunked decode: ids on XCD x are {x, x+8, ...}; chunk start x*q+min(x,r)
    const int total = nbx * 41;
    const int q = total >> 3, r = total & 7;
    const int x = blockIdx.x & 7;
    const int j = blockIdx.x >> 3;
    const int wrk = x * q + min(x, r) + j;
    const int by = wrk / nbx, bx = wrk - by * nbx;
    const int bm = by * 128;
    const int bn = bx * BN;

    f32x4 acc[4][NF];
    f32x4 zz = {0.f, 0.f, 0.f, 0.f};
    #pragma unroll
    for (int i = 0; i < 4; ++i)
        #pragma unroll
        for (int jj = 0; jj < NF; ++jj) acc[i][jj] = zz;

    const int nk = K >> 6;

    // stage A (128x64) + B (BNx64) for k-chunk kt into buffer buf: 6 gll16 per thread.
    // 16B slot s=(row,piece): LDS linear, global source piece = piece^(row&7).
    auto stage = [&](int buf, int kt) {
        u16* abase = &lds[buf][0];
        #pragma unroll
        for (int i = 0; i < 4; ++i) {
            int slot = tid + i * 256;
            int row = slot >> 3, piece = slot & 7;
            int sp = piece ^ (row & 7);
            const u16* src = A + (size_t)min(bm + row, M - 1) * K + kt * 64 + sp * 8;
            gll16(src, abase + ((tid & ~63) + i * 256) * 8);
        }
        u16* bbase = &lds[buf][128 * 64];
        #pragma unroll
        for (int i = 0; i < NF; ++i) {
            int slot = tid + i * 256;
            int row = slot >> 3, piece = slot & 7;
            int sp = piece ^ (row & 7);
            const u16* src = Bt + (size_t)(bn + row) * K + kt * 64 + sp * 8;
            gll16(src, bbase + ((tid & ~63) + i * 256) * 8);
        }
    };

    stage(0, 0);
    stage(1, 1);
    for (int kt = 0; kt < nk; ++kt) {
        const int cur = kt % 3;
        if (kt + 2 < nk) stage(cur == 0 ? 2 : cur - 1, kt + 2);   // (kt+2)%3
        // counted-vmcnt barrier: batch kt landed; later batches stay in flight.
        if (kt + 2 < nk)      asm volatile("s_waitcnt vmcnt(12)\ns_barrier" ::: "memory");
        else if (kt + 1 < nk) asm volatile("s_waitcnt vmcnt(6)\ns_barrier" ::: "memory");
        else                  asm volatile("s_waitcnt vmcnt(0)\ns_barrier" ::: "memory");
        bf16x8 af[4][2], bfr[NF][2];
        #pragma unroll
        for (int mi = 0; mi < 4; ++mi) {
            int row = wm * 64 + mi * 16 + lr;
            #pragma unroll
            for (int ks = 0; ks < 2; ++ks)
                af[mi][ks] = *(const bf16x8*)&lds[cur][row * 64 + (((lq + 4 * ks) ^ (row & 7)) << 3)];
        }
        #pragma unroll
        for (int ni = 0; ni < NF; ++ni) {
            int row = wn * (BN / 2) + ni * 16 + lr;
            #pragma unroll
            for (int ks = 0; ks < 2; ++ks)
                bfr[ni][ks] = *(const bf16x8*)&lds[cur][128 * 64 + row * 64 + (((lq + 4 * ks) ^ (row & 7)) << 3)];
        }
        #pragma unroll
        for (int mi = 0; mi < 4; ++mi)
            #pragma unroll
            for (int ni = 0; ni < NF; ++ni) {
                acc[mi][ni] = __builtin_amdgcn_mfma_f32_16x16x32_bf16(af[mi][0], bfr[ni][0], acc[mi][ni], 0, 0, 0);
                acc[mi][ni] = __builtin_amdgcn_mfma_f32_16x16x32_bf16(af[mi][1], bfr[ni][1], acc[mi][ni], 0, 0, 0);
            }
        // reads of lds[cur] are all consumed (lgkm waits before MFMAs); fence re-staging.
        asm volatile("s_barrier" ::: "memory");
    }

    // epilogue: D element (row = 4*lq + r within 16-tile, col = lr)
    #pragma unroll
    for (int mi = 0; mi < 4; ++mi) {
        #pragma unroll
        for (int ni = 0; ni < NF; ++ni) {
            int col = bn + wn * (BN / 2) + ni * 16 + lr;
            float bv = 0.f;
            if constexpr (EPI != 1) bv = bias[col];
            #pragma unroll
            for (int rr = 0; rr < 4; ++rr) {
                int m = bm + wm * 64 + mi * 16 + 4 * lq + rr;
                if (m < M) {
                    float v = acc[mi][ni][rr] + bv;
                    if constexpr (EPI == 2) v = fmaxf(v, 0.f);
                    if constexpr (EPI == 3 || EPI == 4) v += resid[(size_t)m * ldc + col];
                    if constexpr (EPI == 0 || EPI == 3) {
                        ((float*)Cout)[(size_t)m * ldc + col] = v;
                    } else if constexpr (EPI == 4) {
                        int b = m / 1296, t = m - b * 1296;
                        ((float*)Cout)[(size_t)(b * 768 + col) * 1296 + t] = v;
                    } else {
                        ((u16*)Cout)[(size_t)m * ldc + col] = f2bf(v);
                    }
                }
            }
        }
    }
}

// ---------------- flash attention v4: swapped QK^T (lane-local q rows) ----------------
// 1D grid of 528 blocks; decode keeps all 11 blocks of a bh on one XCD (id%8 == bh%8).
// Wave-unit u = bx*4+wid in [0,40]: q-tiles q0S=16u (u<40) and q0L=16*(80-u).
// Per k-visit (KVBLK=64): K/V tiles double-buffered in LDS (global_load_lds, swizzled source).
// QK^T computed as mfma(K,Q): D col=lane&15 = q, row=4*lq+reg = k  ->  per-q softmax state
// is ONE scalar per lane; reduce = in-lane tree + shfl_xor(16)/(32); P->bf16 via cvt_pk pairs;
// PV as O^T = mfma(V^T, P^T) with unchanged fragment reads.
__global__ __launch_bounds__(256, 2) void attn_k(const u16* __restrict__ qkv, const u16* __restrict__ vt,
                                                 u16* __restrict__ ao) {
    const float SCALE = 0.03608439182435161f;   // 768^-0.5
    __shared__ __align__(16) u16 kv[2][2][4096]; // [buf][K/V][64 rows x 64 cols]
    __shared__ __align__(16) u16 plds[4][16 * 72];
    const int tid = threadIdx.x;
    const int wid = tid >> 6, l = tid & 63;
    // XCD-affinity decode: id%8 = bh%8
    const int id = blockIdx.x;
    const int xr = id & 7, sl = id >> 3;
    const int g = sl / 11, bx = sl - g * 11;
    const int bh = g * 8 + xr;
    const int b = bh / 12, h = bh % 12;
    const int uu = bx * 4 + wid;
    const int u = min(uu, 40);
    const bool valid = (uu <= 40);
    const int lr = l & 15, lq = l >> 4;
    const int q0S = 16 * u, q0L = 16 * (80 - u);
    const bool hasS = valid && (u < 40);
    const int nktS = (u < 40) ? (((q0S + 15) >> 6) + 1) : 0;
    const int nktL = ((q0L + 15) >> 6) + 1;
    const int umin = min(bx * 4, 40);
    const int nktmax = ((16 * (80 - umin) + 15) >> 6) + 1;

    const u16* kbase = qkv + (size_t)(b * 1296) * 2304 + 768 + h * 64;
    const u16* vbase = vt + (size_t)bh * 64 * 1344;
    u16* pl = &plds[wid][0];

    // Q fragments: row/col = q0+lr, contraction = d (same frag pattern for A and B roles)
    const u16* qpS = qkv + (size_t)(b * 1296 + q0S + lr) * 2304 + h * 64;
    const u16* qpL = qkv + (size_t)(b * 1296 + q0L + lr) * 2304 + h * 64;
    bf16x8 qS0 = *(const bf16x8*)(qpS + 8 * lq);
    bf16x8 qS1 = *(const bf16x8*)(qpS + 32 + 8 * lq);
    bf16x8 qL0 = *(const bf16x8*)(qpL + 8 * lq);
    bf16x8 qL1 = *(const bf16x8*)(qpL + 32 + 8 * lq);

    f32x4 zz = {0.f, 0.f, 0.f, 0.f};
    const float NEG = -__builtin_inff();
    f32x4 oS[4], oL[4];
    float mS = NEG, mL = NEG, lS = 0.f, lL = 0.f;
    #pragma unroll
    for (int i = 0; i < 4; ++i) { oS[i] = zz; oL[i] = zz; }

    // cooperative stage of K+V tiles for k0 = kt*64 into buffer `buf`.
    // global_load_lds dest = wave-uniform base + lane*16B; 512 slots per tile, wave w
    // section i covers slots i*256 + w*64 .. +63.  Linear LDS slot (row,piece) receives
    // global piece piece^(row&7) (source-side swizzle); readers apply the same XOR.
    auto stage = [&](int buf, int kt) {
        const int k0 = kt * 64;
        #pragma unroll
        for (int i = 0; i < 2; ++i) {
            int slot = tid + i * 256;      // 0..511 : 16B slots
            int row = slot >> 3;           // k index 0..63
            int piece = slot & 7;
            int sp = piece ^ (row & 7);
            int tc = min(k0 + row, 1295);
            gll16(kbase + (size_t)tc * 2304 + sp * 8,
                  &kv[buf][0][((tid & 0xFFFFFFC0) + i * 256) * 8]);
        }
        #pragma unroll
        for (int i = 0; i < 2; ++i) {
            int slot = tid + i * 256;
            int row = slot >> 3;           // d index 0..63
            int piece = slot & 7;
            int sp = piece ^ (row & 7);
            gll16(vbase + (size_t)row * 1344 + k0 + sp * 8,
                  &kv[buf][1][((tid & 0xFFFFFFC0) + i * 256) * 8]);
        }
    };

    bf16x8 kb[4][2], vb[4][2];

    auto visit = [&](int q0, bf16x8 qa0, bf16x8 qa1, f32x4 (&o)[4],
                     float& mrow, float& lsum, int k0) {
        const int qrow = q0 + lr;          // this lane's q row
        f32x4 s[4];
        __builtin_amdgcn_s_setprio(1);
        #pragma unroll
        for (int nt = 0; nt < 4; ++nt) {
            f32x4 a = zz;
            a = __builtin_amdgcn_mfma_f32_16x16x32_bf16(kb[nt][0], qa0, a, 0, 0, 0);
            a = __builtin_amdgcn_mfma_f32_16x16x32_bf16(kb[nt][1], qa1, a, 0, 0, 0);
            s[nt] = a;
        }
        __builtin_amdgcn_s_setprio(0);
        // mask (raw scores) + in-lane max tree
        float mnt[4];
        #pragma unroll
        for (int nt = 0; nt < 4; ++nt) {
            #pragma unroll
            for (int r = 0; r < 4; ++r) {
                int k = k0 + nt * 16 + 4 * lq + r;
                s[nt][r] = (k <= qrow) ? s[nt][r] : NEG;
            }
            mnt[nt] = fmaxf(fmaxf(s[nt][0], s[nt][1]), fmaxf(s[nt][2], s[nt][3]));
        }
        float mx = fmaxf(fmaxf(mnt[0], mnt[1]), fmaxf(mnt[2], mnt[3]));
        mx = fmaxf(mx, __shfl_xor(mx, 16));
        mx = fmaxf(mx, __shfl_xor(mx, 32));
        float nm = fmaxf(mrow, mx);
        float alpha = __expf(SCALE * (mrow - nm));
        mrow = nm;
        float nbase = -SCALE * nm;
        float tnt[4];
        #pragma unroll
        for (int nt = 0; nt < 4; ++nt) {
            #pragma unroll
            for (int r = 0; r < 4; ++r) {
                float p = __expf(fmaf(s[nt][r], SCALE, nbase));   // masked -inf -> 0
                s[nt][r] = p;
            }
            tnt[nt] = (s[nt][0] + s[nt][1]) + (s[nt][2] + s[nt][3]);
        }
        float ts = (tnt[0] + tnt[1]) + (tnt[2] + tnt[3]);
        ts += __shfl_xor(ts, 16);
        ts += __shfl_xor(ts, 32);
        lsum = lsum * alpha + ts;
        #pragma unroll
        for (int dt = 0; dt < 4; ++dt) o[dt] *= alpha;
        // P^T store: lane q=lr owns row lr; 4 consecutive k per reg-quad -> one 8B write per nt
        #pragma unroll
        for (int nt = 0; nt < 4; ++nt) {
            bf16x4 pv = __builtin_convertvector(s[nt], bf16x4);
            *(bf16x4*)&pl[lr * 72 + nt * 16 + 4 * lq] = pv;
        }
        __builtin_amdgcn_wave_barrier();
        bf16x8 pa0 = *(const bf16x8*)&pl[lr * 72 + 8 * lq];
        bf16x8 pa1 = *(const bf16x8*)&pl[lr * 72 + 32 + 8 * lq];
        __builtin_amdgcn_s_setprio(1);
        #pragma unroll
        for (int dt = 0; dt < 4; ++dt) {
            o[dt] = __builtin_amdgcn_mfma_f32_16x16x32_bf16(vb[dt][0], pa0, o[dt], 0, 0, 0);
            o[dt] = __builtin_amdgcn_mfma_f32_16x16x32_bf16(vb[dt][1], pa1, o[dt], 0, 0, 0);
        }
        __builtin_amdgcn_s_setprio(0);
        __builtin_amdgcn_wave_barrier();  // protect P buffer before next overwrite
    };

    stage(0, 0);
    for (int kt = 0; kt < nktmax; ++kt) {
        const int cur = kt & 1;
        const int k0 = kt * 64;
        __syncthreads();                       // stage(cur) complete; prior reads of cur^1 done
        if (kt + 1 < nktmax) stage(cur ^ 1, kt + 1);
        // load K/V fragments from LDS (swizzled read)
        #pragma unroll
        for (int nt = 0; nt < 4; ++nt) {
            int krow = nt * 16 + lr;
            kb[nt][0] = *(const bf16x8*)&kv[cur][0][krow * 64 + ((lq ^ (krow & 7)) << 3)];
            kb[nt][1] = *(const bf16x8*)&kv[cur][0][krow * 64 + (((lq + 4) ^ (krow & 7)) << 3)];
        }
        #pragma unroll
        for (int dt = 0; dt < 4; ++dt) {
            int vrow = dt * 16 + lr;
            vb[dt][0] = *(const bf16x8*)&kv[cur][1][vrow * 64 + ((lq ^ (vrow & 7)) << 3)];
            vb[dt][1] = *(const bf16x8*)&kv[cur][1][vrow * 64 + (((lq + 4) ^ (vrow & 7)) << 3)];
        }
        if (valid && kt < nktS) visit(q0S, qS0, qS1, oS, mS, lS, k0);
        if (valid && kt < nktL) visit(q0L, qL0, qL1, oL, mL, lL, k0);
    }

    if (valid) {
        // O^T layout: lane holds q=q0+lr, d = dt*16 + 4*lq + r  -> 8B packed stores
        if (hasS) {
            float inv = 1.f / lS;
            u16* aoS = ao + (size_t)(b * 1296 + q0S + lr) * 768 + h * 64 + 4 * lq;
            #pragma unroll
            for (int dt = 0; dt < 4; ++dt) {
                f32x4 ov = oS[dt] * inv;
                *(bf16x4*)(aoS + dt * 16) = __builtin_convertvector(ov, bf16x4);
            }
        }
        float invL = 1.f / lL;
        u16* aoL = ao + (size_t)(b * 1296 + q0L + lr) * 768 + h * 64 + 4 * lq;
        #pragma unroll
        for (int dt = 0; dt < 4; ++dt) {
            f32x4 ov = oL[dt] * invL;
            *(bf16x4*)(aoL + dt * 16) = __builtin_convertvector(ov, bf16x4);
        }
    }
}

extern "C" void kernel_launch(void* const* d_in, const int* in_sizes, int n_in,
                              void* d_out, int out_size, void* d_ws, size_t ws_size,
                              hipStream_t stream) {
    const float* x      = (const float*)d_in[0];
    const float* conv_w = (const float*)d_in[1];
    const float* conv_b = (const float*)d_in[2];
    const float* wq     = (const float*)d_in[3];
    const float* wk     = (const float*)d_in[4];
    const float* wv     = (const float*)d_in[5];
    const float* wo     = (const float*)d_in[6];
    const float* bo     = (const float*)d_in[7];
    const float* w1     = (const float*)d_in[8];
    const float* b1     = (const float*)d_in[9];
    const float* w2     = (const float*)d_in[10];
    const float* b2     = (const float*)d_in[11];
    const float* ln1g   = (const float*)d_in[12];
    const float* ln1b   = (const float*)d_in[13];
    const float* ln2g   = (const float*)d_in[14];
    const float* ln2b   = (const float*)d_in[15];

    char* ws = (char*)d_ws;
    size_t off = 0;
    auto alloc = [&](size_t bytes) { char* p = ws + off; off = (off + bytes + 255) & ~(size_t)255; return p; };
    u16*   convw_bf = (u16*)alloc((size_t)768 * 768 * 2);
    u16*   wqkv_t   = (u16*)alloc((size_t)2304 * 768 * 2);
    u16*   wo_t     = (u16*)alloc((size_t)768 * 768 * 2);
    u16*   w1_t     = (u16*)alloc((size_t)3072 * 768 * 2);
    u16*   w2_t     = (u16*)alloc((size_t)768 * 3072 * 2);
    float* tok      = (float*)alloc((size_t)5184 * 768 * 4);
    u16*   hbuf     = (u16*)alloc((size_t)5184 * 768 * 2);
    u16*   apao     = (u16*)alloc((size_t)5184 * 768 * 2);   // patches, later attention output
    size_t qkv_bytes = ((size_t)5184 * 2304 * 2 + 255) & ~(size_t)255;
    size_t vt_bytes  = (size_t)48 * 64 * 1344 * 2;
    size_t a1_bytes  = (size_t)5184 * 3072 * 2;
    size_t big_bytes = qkv_bytes + vt_bytes;
    if (a1_bytes > big_bytes) big_bytes = a1_bytes;
    char* big = alloc(big_bytes);
    u16* qkvb = (u16*)big;
    u16* vtb  = (u16*)(big + qkv_bytes);
    u16* a1   = (u16*)big;   // overlays qkv+vt (dead after attention)

    // 1. weight prep
    convcvt_k<<<576, 256, 0, stream>>>(conv_w, convw_bf);
    wtrans_k<<<dim3(24, 24), 256, 0, stream>>>(wq, wqkv_t, 768, 768);
    wtrans_k<<<dim3(24, 24), 256, 0, stream>>>(wk, wqkv_t + 768 * 768, 768, 768);
    wtrans_k<<<dim3(24, 24), 256, 0, stream>>>(wv, wqkv_t + 2 * 768 * 768, 768, 768);
    wtrans_k<<<dim3(24, 24), 256, 0, stream>>>(wo, wo_t, 768, 768);
    wtrans_k<<<dim3(96, 24), 256, 0, stream>>>(w1, w1_t, 768, 3072);
    wtrans_k<<<dim3(24, 96), 256, 0, stream>>>(w2, w2_t, 3072, 768);
    // 2. patch gather
    patch_k<<<972, 256, 0, stream>>>(x, apao);
    // 3. patch-embed GEMM -> tok (f32)
    gemm_k<64, 0><<<12 * 41, 256, 0, stream>>>(apao, convw_bf, conv_b, nullptr, tok, 768, 768, 12);
    // 4. LN1 -> h (bf16)
    ln_k<<<1296, 256, 0, stream>>>(tok, ln1g, ln1b, hbuf);
    // 5. fused QKV GEMM -> qkv (bf16)
    gemm_k<64, 1><<<36 * 41, 256, 0, stream>>>(hbuf, wqkv_t, nullptr, nullptr, qkvb, 768, 2304, 36);
    // 6. V transpose
    vtrans_k<<<dim3(41, 2, 48), 256, 0, stream>>>(qkvb, vtb);
    // 7. attention -> ao (bf16, reuses patch buffer): balanced + LDS-staged, XCD-affine, swapped-QK
    attn_k<<<528, 256, 0, stream>>>(qkvb, vtb, apao);
    // 8. output proj + residual -> tok
    gemm_k<64, 3><<<12 * 41, 256, 0, stream>>>(apao, wo_t, bo, tok, tok, 768, 768, 12);
    // 9. LN2 -> h
    ln_k<<<1296, 256, 0, stream>>>(tok, ln2g, ln2b, hbuf);
    // 10. MLP1 (relu) -> a1 (bf16)
    gemm_k<64, 2><<<48 * 41, 256, 0, stream>>>(hbuf, w1_t, b1, nullptr, a1, 768, 3072, 48);
    // 11. MLP2 + residual, store transposed (B,E,36,36) -> d_out (f32)
    gemm_k<64, 4><<<12 * 41, 256, 0, stream>>>(a1, w2_t, b2, tok, d_out, 3072, 768, 12);
}

// Round 8
// 330.946 us; speedup vs baseline: 1.0574x; 1.0574x over previous
//
#include <hip/hip_runtime.h>

typedef unsigned short u16;
typedef unsigned int u32;
typedef unsigned long long u64;
typedef float f32x4 __attribute__((ext_vector_type(4)));
typedef __bf16 bf16x8 __attribute__((ext_vector_type(8)));
typedef __bf16 bf16x4 __attribute__((ext_vector_type(4)));
typedef u16 u16x8 __attribute__((ext_vector_type(8)));

#define DEV __device__ __forceinline__

// ---- constants for this problem ----
// B=4, T=1296 (36x36 patches), E=768, H=12, HD=64, M = B*T = 5184
// patch K = C_IN*P*P = 3*16*16 = 768

DEV u16 f2bf(float f) {
    union { float f; u32 u; } un; un.f = f;
    u32 u = un.u;
    return (u16)((u + 0x7fffu + ((u >> 16) & 1u)) >> 16);
}

DEV void gll16(const u16* src, u16* dst) {
    auto g = (const __attribute__((address_space(1))) u32*)(src);
    auto s = (__attribute__((address_space(3))) u32*)(dst);
    __builtin_amdgcn_global_load_lds(g, s, 16, 0, 0);
}

// ---------------- weight convert / transpose ----------------
__global__ void convcvt_k(const float* __restrict__ src, u16* __restrict__ dst) {
    int i = blockIdx.x * 256 + threadIdx.x;          // one float4 per thread
    f32x4 v = ((const f32x4*)src)[i];
    union { u16 q[4]; u64 ll; } un;
    #pragma unroll
    for (int j = 0; j < 4; ++j) un.q[j] = f2bf(v[j]);
    ((u64*)dst)[i] = un.ll;
}

// src: f32 [K][N] row-major; dst: bf16 [N][K]
__global__ void wtrans_k(const float* __restrict__ src, u16* __restrict__ dst, int K, int N) {
    __shared__ float tile[32][33];
    int n0 = blockIdx.x * 32, k0 = blockIdx.y * 32;
    int tx = threadIdx.x & 31, ty = threadIdx.x >> 5;   // 32 x 8
    #pragma unroll
    for (int i = 0; i < 32; i += 8)
        tile[ty + i][tx] = src[(size_t)(k0 + ty + i) * N + n0 + tx];
    __syncthreads();
    #pragma unroll
    for (int i = 0; i < 32; i += 8)
        dst[(size_t)(n0 + ty + i) * K + k0 + tx] = f2bf(tile[tx][ty + i]);
}

// ---------------- patch gather: x (B,3,576,576) -> A [5184][768] bf16 ----------------
__global__ void patch_k(const float* __restrict__ x, u16* __restrict__ out) {
    int idx = blockIdx.x * 256 + threadIdx.x;   // [b][c][i][p][j], j innermost
    int j = idx % 36; int r1 = idx / 36;
    int p = r1 % 16;  int r2 = r1 / 16;
    int i = r2 % 36;  int r3 = r2 / 36;
    int c = r3 % 3;   int b = r3 / 3;
    const f32x4* src = (const f32x4*)(x + (size_t)((b * 3 + c) * 576 + i * 16 + p) * 576 + j * 16);
    u16x8 lo, hi;
    #pragma unroll
    for (int k = 0; k < 2; ++k) {
        f32x4 v = src[k];
        #pragma unroll
        for (int e = 0; e < 4; ++e) lo[k * 4 + e] = f2bf(v[e]);
    }
    #pragma unroll
    for (int k = 0; k < 2; ++k) {
        f32x4 v = src[2 + k];
        #pragma unroll
        for (int e = 0; e < 4; ++e) hi[k * 4 + e] = f2bf(v[e]);
    }
    u16* dst = out + (size_t)(b * 1296 + i * 36 + j) * 768 + c * 256 + p * 16;
    *(u16x8*)dst = lo;
    *(u16x8*)(dst + 8) = hi;
}

// ---------------- LayerNorm: f32 [5184][768] -> bf16 [5184][768] ----------------
__global__ __launch_bounds__(256) void ln_k(const float* __restrict__ x, const float* __restrict__ g,
                                            const float* __restrict__ bta, u16* __restrict__ out) {
    int row = blockIdx.x * 4 + (threadIdx.x >> 6);
    int l = threadIdx.x & 63;
    const float* xr = x + (size_t)row * 768;
    float v[12]; float s = 0.f, s2 = 0.f;
    #pragma unroll
    for (int i = 0; i < 12; ++i) { v[i] = xr[l + 64 * i]; s += v[i]; s2 += v[i] * v[i]; }
    #pragma unroll
    for (int off = 32; off; off >>= 1) { s += __shfl_xor(s, off); s2 += __shfl_xor(s2, off); }
    float mu = s * (1.f / 768.f);
    float var = s2 * (1.f / 768.f) - mu * mu;
    float rs = rsqrtf(var + 1e-5f);
    u16* orow = out + (size_t)row * 768;
    #pragma unroll
    for (int i = 0; i < 12; ++i) {
        int c = l + 64 * i;
        orow[c] = f2bf((v[i] - mu) * rs * g[c] + bta[c]);
    }
}

// ---------------- V transpose: qkv[.][1536+h*64+d] -> vt[bh][d][t] (t padded to 1344) ----------------
__global__ void vtrans_k(const u16* __restrict__ qkv, u16* __restrict__ vt) {
    __shared__ u16 tile[32][33];
    int bh = blockIdx.z; int b = bh / 12, h = bh % 12;
    int t0 = blockIdx.x * 32, d0 = blockIdx.y * 32;
    int tx = threadIdx.x & 31, ty = threadIdx.x >> 5;
    #pragma unroll
    for (int i = 0; i < 32; i += 8) {
        int t = t0 + ty + i; int tc = min(t, 1295);
        tile[ty + i][tx] = qkv[(size_t)(b * 1296 + tc) * 2304 + 1536 + h * 64 + d0 + tx];
    }
    __syncthreads();
    #pragma unroll
    for (int i = 0; i < 32; i += 8) {
        int d = d0 + ty + i; int t = t0 + tx;
        if (t < 1296) vt[(size_t)(bh * 64 + d) * 1344 + t] = tile[tx][ty + i];
    }
}

// ---------------- GEMM v4: C[M][N] = A[M][K] @ Bt[N][K]^T (+epilogue) ----------------
// BK=64 (128B LDS rows), piece^(row&7) swizzle (conflict-free), XCD-chunked bijective
// decode, DOUBLE-buffered LDS with COUNTED vmcnt before s_barrier (T4): the just-issued
// prefetch batch (kt+1) stays in flight across the read+MFMA phase; only the tail drains.
// Per-wave vmcnt(N) before s_barrier ==> at barrier exit ALL waves' batch-kt loads landed.
// EPI: 0 = +bias, f32 store        (patch embed -> tok)
//      1 = bf16 store, no bias     (qkv)
//      2 = +bias, relu, bf16 store (mlp1 -> a1)
//      3 = +bias, +resid, f32 store(proj -> tok)
//      4 = +bias, +resid, f32 store TRANSPOSED to (B,E,T)   (mlp2 -> d_out)
template <int BN, int EPI>
__global__ __launch_bounds__(256) void gemm_k(const u16* __restrict__ A, const u16* __restrict__ Bt,
                                              const float* __restrict__ bias, const float* __restrict__ resid,
                                              void* __restrict__ Cout, int K, int ldc, int nbx) {
    constexpr int M = 5184;
    constexpr int NF = BN / 32;
    // 2 buffers x (128 A-rows + BN B-rows) x 64 u16 (128B rows)
    __shared__ __align__(16) u16 lds[2][(128 + BN) * 64];
    const int tid = threadIdx.x;
    const int l = tid & 63, w = tid >> 6;
    const int lr = l & 15, lq = l >> 4;
    const int wm = w >> 1, wn = w & 1;

    // bijective XCD-chunked decode: ids on XCD x are {x, x+8, ...}; chunk start x*q+min(x,r)
    const int total = nbx * 41;
    const int q = total >> 3, r = total & 7;
    const int x = blockIdx.x & 7;
    const int j = blockIdx.x >> 3;
    const int wrk = x * q + min(x, r) + j;
    const int by = wrk / nbx, bx = wrk - by * nbx;
    const int bm = by * 128;
    const int bn = bx * BN;

    f32x4 acc[4][NF];
    f32x4 zz = {0.f, 0.f, 0.f, 0.f};
    #pragma unroll
    for (int i = 0; i < 4; ++i)
        #pragma unroll
        for (int jj = 0; jj < NF; ++jj) acc[i][jj] = zz;

    const int nk = K >> 6;

    // stage A (128x64) + B (BNx64) for k-chunk kt into buffer buf: 4+NF gll16 per thread.
    // 16B slot s=(row,piece): LDS linear, global source piece = piece^(row&7).
    auto stage = [&](int buf, int kt) {
        u16* abase = &lds[buf][0];
        #pragma unroll
        for (int i = 0; i < 4; ++i) {
            int slot = tid + i * 256;
            int row = slot >> 3, piece = slot & 7;
            int sp = piece ^ (row & 7);
            const u16* src = A + (size_t)min(bm + row, M - 1) * K + kt * 64 + sp * 8;
            gll16(src, abase + ((tid & ~63) + i * 256) * 8);
        }
        u16* bbase = &lds[buf][128 * 64];
        #pragma unroll
        for (int i = 0; i < NF; ++i) {
            int slot = tid + i * 256;
            int row = slot >> 3, piece = slot & 7;
            int sp = piece ^ (row & 7);
            const u16* src = Bt + (size_t)(bn + row) * K + kt * 64 + sp * 8;
            gll16(src, bbase + ((tid & ~63) + i * 256) * 8);
        }
    };

    stage(0, 0);
    for (int kt = 0; kt < nk; ++kt) {
        const int cur = kt & 1;
        if (kt + 1 < nk) {
            stage(cur ^ 1, kt + 1);
            // batch kt landed for THIS wave; batch kt+1 (4+NF loads) stays in flight.
            // barrier => every wave has passed its own vmcnt => whole tile kt visible.
            if constexpr (BN == 128) asm volatile("s_waitcnt vmcnt(8)\ns_barrier" ::: "memory");
            else                     asm volatile("s_waitcnt vmcnt(6)\ns_barrier" ::: "memory");
        } else {
            asm volatile("s_waitcnt vmcnt(0)\ns_barrier" ::: "memory");
        }
        bf16x8 af[4][2], bfr[NF][2];
        #pragma unroll
        for (int mi = 0; mi < 4; ++mi) {
            int row = wm * 64 + mi * 16 + lr;
            #pragma unroll
            for (int ks = 0; ks < 2; ++ks)
                af[mi][ks] = *(const bf16x8*)&lds[cur][row * 64 + (((lq + 4 * ks) ^ (row & 7)) << 3)];
        }
        #pragma unroll
        for (int ni = 0; ni < NF; ++ni) {
            int row = wn * (BN / 2) + ni * 16 + lr;
            #pragma unroll
            for (int ks = 0; ks < 2; ++ks)
                bfr[ni][ks] = *(const bf16x8*)&lds[cur][128 * 64 + row * 64 + (((lq + 4 * ks) ^ (row & 7)) << 3)];
        }
        #pragma unroll
        for (int mi = 0; mi < 4; ++mi)
            #pragma unroll
            for (int ni = 0; ni < NF; ++ni) {
                acc[mi][ni] = __builtin_amdgcn_mfma_f32_16x16x32_bf16(af[mi][0], bfr[ni][0], acc[mi][ni], 0, 0, 0);
                acc[mi][ni] = __builtin_amdgcn_mfma_f32_16x16x32_bf16(af[mi][1], bfr[ni][1], acc[mi][ni], 0, 0, 0);
            }
        // all reads of lds[cur] consumed (lgkm waits precede MFMA use); fence re-staging.
        asm volatile("s_barrier" ::: "memory");
    }

    // epilogue: D element (row = 4*lq + r within 16-tile, col = lr)
    #pragma unroll
    for (int mi = 0; mi < 4; ++mi) {
        #pragma unroll
        for (int ni = 0; ni < NF; ++ni) {
            int col = bn + wn * (BN / 2) + ni * 16 + lr;
            float bv = 0.f;
            if constexpr (EPI != 1) bv = bias[col];
            #pragma unroll
            for (int rr = 0; rr < 4; ++rr) {
                int m = bm + wm * 64 + mi * 16 + 4 * lq + rr;
                if (m < M) {
                    float v = acc[mi][ni][rr] + bv;
                    if constexpr (EPI == 2) v = fmaxf(v, 0.f);
                    if constexpr (EPI == 3 || EPI == 4) v += resid[(size_t)m * ldc + col];
                    if constexpr (EPI == 0 || EPI == 3) {
                        ((float*)Cout)[(size_t)m * ldc + col] = v;
                    } else if constexpr (EPI == 4) {
                        int b = m / 1296, t = m - b * 1296;
                        ((float*)Cout)[(size_t)(b * 768 + col) * 1296 + t] = v;
                    } else {
                        ((u16*)Cout)[(size_t)m * ldc + col] = f2bf(v);
                    }
                }
            }
        }
    }
}

// ---------------- flash attention v4: swapped QK^T (lane-local q rows) ----------------
// 1D grid of 528 blocks; decode keeps all 11 blocks of a bh on one XCD (id%8 == bh%8).
// Wave-unit u = bx*4+wid in [0,40]: q-tiles q0S=16u (u<40) and q0L=16*(80-u).
// Per k-visit (KVBLK=64): K/V tiles double-buffered in LDS (global_load_lds, swizzled source).
// QK^T computed as mfma(K,Q): D col=lane&15 = q, row=4*lq+reg = k  ->  per-q softmax state
// is ONE scalar per lane; reduce = in-lane tree + shfl_xor(16)/(32); P->bf16 via cvt_pk pairs;
// PV as O^T = mfma(V^T, P^T) with unchanged fragment reads.
__global__ __launch_bounds__(256, 2) void attn_k(const u16* __restrict__ qkv, const u16* __restrict__ vt,
                                                 u16* __restrict__ ao) {
    const float SCALE = 0.03608439182435161f;   // 768^-0.5
    __shared__ __align__(16) u16 kv[2][2][4096]; // [buf][K/V][64 rows x 64 cols]
    __shared__ __align__(16) u16 plds[4][16 * 72];
    const int tid = threadIdx.x;
    const int wid = tid >> 6, l = tid & 63;
    // XCD-affinity decode: id%8 = bh%8
    const int id = blockIdx.x;
    const int xr = id & 7, sl = id >> 3;
    const int g = sl / 11, bx = sl - g * 11;
    const int bh = g * 8 + xr;
    const int b = bh / 12, h = bh % 12;
    const int uu = bx * 4 + wid;
    const int u = min(uu, 40);
    const bool valid = (uu <= 40);
    const int lr = l & 15, lq = l >> 4;
    const int q0S = 16 * u, q0L = 16 * (80 - u);
    const bool hasS = valid && (u < 40);
    const int nktS = (u < 40) ? (((q0S + 15) >> 6) + 1) : 0;
    const int nktL = ((q0L + 15) >> 6) + 1;
    const int umin = min(bx * 4, 40);
    const int nktmax = ((16 * (80 - umin) + 15) >> 6) + 1;

    const u16* kbase = qkv + (size_t)(b * 1296) * 2304 + 768 + h * 64;
    const u16* vbase = vt + (size_t)bh * 64 * 1344;
    u16* pl = &plds[wid][0];

    // Q fragments: row/col = q0+lr, contraction = d (same frag pattern for A and B roles)
    const u16* qpS = qkv + (size_t)(b * 1296 + q0S + lr) * 2304 + h * 64;
    const u16* qpL = qkv + (size_t)(b * 1296 + q0L + lr) * 2304 + h * 64;
    bf16x8 qS0 = *(const bf16x8*)(qpS + 8 * lq);
    bf16x8 qS1 = *(const bf16x8*)(qpS + 32 + 8 * lq);
    bf16x8 qL0 = *(const bf16x8*)(qpL + 8 * lq);
    bf16x8 qL1 = *(const bf16x8*)(qpL + 32 + 8 * lq);

    f32x4 zz = {0.f, 0.f, 0.f, 0.f};
    const float NEG = -__builtin_inff();
    f32x4 oS[4], oL[4];
    float mS = NEG, mL = NEG, lS = 0.f, lL = 0.f;
    #pragma unroll
    for (int i = 0; i < 4; ++i) { oS[i] = zz; oL[i] = zz; }

    // cooperative stage of K+V tiles for k0 = kt*64 into buffer `buf`.
    // global_load_lds dest = wave-uniform base + lane*16B; 512 slots per tile, wave w
    // section i covers slots i*256 + w*64 .. +63.  Linear LDS slot (row,piece) receives
    // global piece piece^(row&7) (source-side swizzle); readers apply the same XOR.
    auto stage = [&](int buf, int kt) {
        const int k0 = kt * 64;
        #pragma unroll
        for (int i = 0; i < 2; ++i) {
            int slot = tid + i * 256;      // 0..511 : 16B slots
            int row = slot >> 3;           // k index 0..63
            int piece = slot & 7;
            int sp = piece ^ (row & 7);
            int tc = min(k0 + row, 1295);
            gll16(kbase + (size_t)tc * 2304 + sp * 8,
                  &kv[buf][0][((tid & 0xFFFFFFC0) + i * 256) * 8]);
        }
        #pragma unroll
        for (int i = 0; i < 2; ++i) {
            int slot = tid + i * 256;
            int row = slot >> 3;           // d index 0..63
            int piece = slot & 7;
            int sp = piece ^ (row & 7);
            gll16(vbase + (size_t)row * 1344 + k0 + sp * 8,
                  &kv[buf][1][((tid & 0xFFFFFFC0) + i * 256) * 8]);
        }
    };

    bf16x8 kb[4][2], vb[4][2];

    auto visit = [&](int q0, bf16x8 qa0, bf16x8 qa1, f32x4 (&o)[4],
                     float& mrow, float& lsum, int k0) {
        const int qrow = q0 + lr;          // this lane's q row
        f32x4 s[4];
        __builtin_amdgcn_s_setprio(1);
        #pragma unroll
        for (int nt = 0; nt < 4; ++nt) {
            f32x4 a = zz;
            a = __builtin_amdgcn_mfma_f32_16x16x32_bf16(kb[nt][0], qa0, a, 0, 0, 0);
            a = __builtin_amdgcn_mfma_f32_16x16x32_bf16(kb[nt][1], qa1, a, 0, 0, 0);
            s[nt] = a;
        }
        __builtin_amdgcn_s_setprio(0);
        // mask (raw scores) + in-lane max tree
        float mnt[4];
        #pragma unroll
        for (int nt = 0; nt < 4; ++nt) {
            #pragma unroll
            for (int r = 0; r < 4; ++r) {
                int k = k0 + nt * 16 + 4 * lq + r;
                s[nt][r] = (k <= qrow) ? s[nt][r] : NEG;
            }
            mnt[nt] = fmaxf(fmaxf(s[nt][0], s[nt][1]), fmaxf(s[nt][2], s[nt][3]));
        }
        float mx = fmaxf(fmaxf(mnt[0], mnt[1]), fmaxf(mnt[2], mnt[3]));
        mx = fmaxf(mx, __shfl_xor(mx, 16));
        mx = fmaxf(mx, __shfl_xor(mx, 32));
        float nm = fmaxf(mrow, mx);
        float alpha = __expf(SCALE * (mrow - nm));
        mrow = nm;
        float nbase = -SCALE * nm;
        float tnt[4];
        #pragma unroll
        for (int nt = 0; nt < 4; ++nt) {
            #pragma unroll
            for (int r = 0; r < 4; ++r) {
                float p = __expf(fmaf(s[nt][r], SCALE, nbase));   // masked -inf -> 0
                s[nt][r] = p;
            }
            tnt[nt] = (s[nt][0] + s[nt][1]) + (s[nt][2] + s[nt][3]);
        }
        float ts = (tnt[0] + tnt[1]) + (tnt[2] + tnt[3]);
        ts += __shfl_xor(ts, 16);
        ts += __shfl_xor(ts, 32);
        lsum = lsum * alpha + ts;
        #pragma unroll
        for (int dt = 0; dt < 4; ++dt) o[dt] *= alpha;
        // P^T store: lane q=lr owns row lr; 4 consecutive k per reg-quad -> one 8B write per nt
        #pragma unroll
        for (int nt = 0; nt < 4; ++nt) {
            bf16x4 pv = __builtin_convertvector(s[nt], bf16x4);
            *(bf16x4*)&pl[lr * 72 + nt * 16 + 4 * lq] = pv;
        }
        __builtin_amdgcn_wave_barrier();
        bf16x8 pa0 = *(const bf16x8*)&pl[lr * 72 + 8 * lq];
        bf16x8 pa1 = *(const bf16x8*)&pl[lr * 72 + 32 + 8 * lq];
        __builtin_amdgcn_s_setprio(1);
        #pragma unroll
        for (int dt = 0; dt < 4; ++dt) {
            o[dt] = __builtin_amdgcn_mfma_f32_16x16x32_bf16(vb[dt][0], pa0, o[dt], 0, 0, 0);
            o[dt] = __builtin_amdgcn_mfma_f32_16x16x32_bf16(vb[dt][1], pa1, o[dt], 0, 0, 0);
        }
        __builtin_amdgcn_s_setprio(0);
        __builtin_amdgcn_wave_barrier();  // protect P buffer before next overwrite
    };

    stage(0, 0);
    for (int kt = 0; kt < nktmax; ++kt) {
        const int cur = kt & 1;
        const int k0 = kt * 64;
        __syncthreads();                       // stage(cur) complete; prior reads of cur^1 done
        if (kt + 1 < nktmax) stage(cur ^ 1, kt + 1);
        // load K/V fragments from LDS (swizzled read)
        #pragma unroll
        for (int nt = 0; nt < 4; ++nt) {
            int krow = nt * 16 + lr;
            kb[nt][0] = *(const bf16x8*)&kv[cur][0][krow * 64 + ((lq ^ (krow & 7)) << 3)];
            kb[nt][1] = *(const bf16x8*)&kv[cur][0][krow * 64 + (((lq + 4) ^ (krow & 7)) << 3)];
        }
        #pragma unroll
        for (int dt = 0; dt < 4; ++dt) {
            int vrow = dt * 16 + lr;
            vb[dt][0] = *(const bf16x8*)&kv[cur][1][vrow * 64 + ((lq ^ (vrow & 7)) << 3)];
            vb[dt][1] = *(const bf16x8*)&kv[cur][1][vrow * 64 + (((lq + 4) ^ (vrow & 7)) << 3)];
        }
        if (valid && kt < nktS) visit(q0S, qS0, qS1, oS, mS, lS, k0);
        if (valid && kt < nktL) visit(q0L, qL0, qL1, oL, mL, lL, k0);
    }

    if (valid) {
        // O^T layout: lane holds q=q0+lr, d = dt*16 + 4*lq + r  -> 8B packed stores
        if (hasS) {
            float inv = 1.f / lS;
            u16* aoS = ao + (size_t)(b * 1296 + q0S + lr) * 768 + h * 64 + 4 * lq;
            #pragma unroll
            for (int dt = 0; dt < 4; ++dt) {
                f32x4 ov = oS[dt] * inv;
                *(bf16x4*)(aoS + dt * 16) = __builtin_convertvector(ov, bf16x4);
            }
        }
        float invL = 1.f / lL;
        u16* aoL = ao + (size_t)(b * 1296 + q0L + lr) * 768 + h * 64 + 4 * lq;
        #pragma unroll
        for (int dt = 0; dt < 4; ++dt) {
            f32x4 ov = oL[dt] * invL;
            *(bf16x4*)(aoL + dt * 16) = __builtin_convertvector(ov, bf16x4);
        }
    }
}

extern "C" void kernel_launch(void* const* d_in, const int* in_sizes, int n_in,
                              void* d_out, int out_size, void* d_ws, size_t ws_size,
                              hipStream_t stream) {
    const float* x      = (const float*)d_in[0];
    const float* conv_w = (const float*)d_in[1];
    const float* conv_b = (const float*)d_in[2];
    const float* wq     = (const float*)d_in[3];
    const float* wk     = (const float*)d_in[4];
    const float* wv     = (const float*)d_in[5];
    const float* wo     = (const float*)d_in[6];
    const float* bo     = (const float*)d_in[7];
    const float* w1     = (const float*)d_in[8];
    const float* b1     = (const float*)d_in[9];
    const float* w2     = (const float*)d_in[10];
    const float* b2     = (const float*)d_in[11];
    const float* ln1g   = (const float*)d_in[12];
    const float* ln1b   = (const float*)d_in[13];
    const float* ln2g   = (const float*)d_in[14];
    const float* ln2b   = (const float*)d_in[15];

    char* ws = (char*)d_ws;
    size_t off = 0;
    auto alloc = [&](size_t bytes) { char* p = ws + off; off = (off + bytes + 255) & ~(size_t)255; return p; };
    u16*   convw_bf = (u16*)alloc((size_t)768 * 768 * 2);
    u16*   wqkv_t   = (u16*)alloc((size_t)2304 * 768 * 2);
    u16*   wo_t     = (u16*)alloc((size_t)768 * 768 * 2);
    u16*   w1_t     = (u16*)alloc((size_t)3072 * 768 * 2);
    u16*   w2_t     = (u16*)alloc((size_t)768 * 3072 * 2);
    float* tok      = (float*)alloc((size_t)5184 * 768 * 4);
    u16*   hbuf     = (u16*)alloc((size_t)5184 * 768 * 2);
    u16*   apao     = (u16*)alloc((size_t)5184 * 768 * 2);   // patches, later attention output
    size_t qkv_bytes = ((size_t)5184 * 2304 * 2 + 255) & ~(size_t)255;
    size_t vt_bytes  = (size_t)48 * 64 * 1344 * 2;
    size_t a1_bytes  = (size_t)5184 * 3072 * 2;
    size_t big_bytes = qkv_bytes + vt_bytes;
    if (a1_bytes > big_bytes) big_bytes = a1_bytes;
    char* big = alloc(big_bytes);
    u16* qkvb = (u16*)big;
    u16* vtb  = (u16*)(big + qkv_bytes);
    u16* a1   = (u16*)big;   // overlays qkv+vt (dead after attention)

    // 1. weight prep
    convcvt_k<<<576, 256, 0, stream>>>(conv_w, convw_bf);
    wtrans_k<<<dim3(24, 24), 256, 0, stream>>>(wq, wqkv_t, 768, 768);
    wtrans_k<<<dim3(24, 24), 256, 0, stream>>>(wk, wqkv_t + 768 * 768, 768, 768);
    wtrans_k<<<dim3(24, 24), 256, 0, stream>>>(wv, wqkv_t + 2 * 768 * 768, 768, 768);
    wtrans_k<<<dim3(24, 24), 256, 0, stream>>>(wo, wo_t, 768, 768);
    wtrans_k<<<dim3(96, 24), 256, 0, stream>>>(w1, w1_t, 768, 3072);
    wtrans_k<<<dim3(24, 96), 256, 0, stream>>>(w2, w2_t, 3072, 768);
    // 2. patch gather
    patch_k<<<972, 256, 0, stream>>>(x, apao);
    // 3. patch-embed GEMM -> tok (f32)
    gemm_k<64, 0><<<12 * 41, 256, 0, stream>>>(apao, convw_bf, conv_b, nullptr, tok, 768, 768, 12);
    // 4. LN1 -> h (bf16)
    ln_k<<<1296, 256, 0, stream>>>(tok, ln1g, ln1b, hbuf);
    // 5. fused QKV GEMM -> qkv (bf16)
    gemm_k<128, 1><<<18 * 41, 256, 0, stream>>>(hbuf, wqkv_t, nullptr, nullptr, qkvb, 768, 2304, 18);
    // 6. V transpose
    vtrans_k<<<dim3(41, 2, 48), 256, 0, stream>>>(qkvb, vtb);
    // 7. attention -> ao (bf16, reuses patch buffer): balanced + LDS-staged, XCD-affine, swapped-QK
    attn_k<<<528, 256, 0, stream>>>(qkvb, vtb, apao);
    // 8. output proj + residual -> tok
    gemm_k<64, 3><<<12 * 41, 256, 0, stream>>>(apao, wo_t, bo, tok, tok, 768, 768, 12);
    // 9. LN2 -> h
    ln_k<<<1296, 256, 0, stream>>>(tok, ln2g, ln2b, hbuf);
    // 10. MLP1 (relu) -> a1 (bf16)
    gemm_k<128, 2><<<24 * 41, 256, 0, stream>>>(hbuf, w1_t, b1, nullptr, a1, 768, 3072, 24);
    // 11. MLP2 + residual, store transposed (B,E,36,36) -> d_out (f32)
    gemm_k<64, 4><<<12 * 41, 256, 0, stream>>>(a1, w2_t, b2, tok, d_out, 3072, 768, 12);
}

// Round 9
// 313.273 us; speedup vs baseline: 1.1171x; 1.0564x over previous
//
#include <hip/hip_runtime.h>

typedef unsigned short u16;
typedef unsigned int u32;
typedef unsigned long long u64;
typedef float f32x4 __attribute__((ext_vector_type(4)));
typedef __bf16 bf16x8 __attribute__((ext_vector_type(8)));
typedef __bf16 bf16x4 __attribute__((ext_vector_type(4)));
typedef u16 u16x8 __attribute__((ext_vector_type(8)));

#define DEV __device__ __forceinline__

// ---- constants ----
// B=4, T=1296 (36x36), E=768, H=12, HD=64, M = B*T = 5184, patch K = 768

DEV u16 f2bf(float f) {
    union { float f; u32 u; } un; un.f = f;
    u32 u = un.u;
    return (u16)((u + 0x7fffu + ((u >> 16) & 1u)) >> 16);
}

DEV void gll16(const u16* src, u16* dst) {
    auto g = (const __attribute__((address_space(1))) u32*)(src);
    auto s = (__attribute__((address_space(3))) u32*)(dst);
    __builtin_amdgcn_global_load_lds(g, s, 16, 0, 0);
}

// ---------------- mega prep kernel: patch gather + conv cvt + 6 weight transposes ----------------
// blocks: [0,972) patch gather; [972,1548) convcvt; [1548,8460) wtrans regions.
__global__ __launch_bounds__(256) void prep_k(
    const float* __restrict__ x, const float* __restrict__ conv_w,
    const float* __restrict__ wq, const float* __restrict__ wk,
    const float* __restrict__ wv, const float* __restrict__ wo,
    const float* __restrict__ w1, const float* __restrict__ w2,
    u16* __restrict__ patches, u16* __restrict__ convw_bf,
    u16* __restrict__ wqkv_t, u16* __restrict__ wo_t,
    u16* __restrict__ w1_t, u16* __restrict__ w2_t) {
    __shared__ float tile[32][33];
    int id = blockIdx.x;
    if (id < 972) {           // ---- patch gather: x -> patches [5184][768] bf16
        int idx = id * 256 + threadIdx.x;   // [b][c][i][p][j]
        int j = idx % 36; int r1 = idx / 36;
        int p = r1 % 16;  int r2 = r1 / 16;
        int i = r2 % 36;  int r3 = r2 / 36;
        int c = r3 % 3;   int b = r3 / 3;
        const f32x4* src = (const f32x4*)(x + (size_t)((b * 3 + c) * 576 + i * 16 + p) * 576 + j * 16);
        u16x8 lo, hi;
        #pragma unroll
        for (int k = 0; k < 2; ++k) {
            f32x4 v = src[k];
            #pragma unroll
            for (int e = 0; e < 4; ++e) lo[k * 4 + e] = f2bf(v[e]);
        }
        #pragma unroll
        for (int k = 0; k < 2; ++k) {
            f32x4 v = src[2 + k];
            #pragma unroll
            for (int e = 0; e < 4; ++e) hi[k * 4 + e] = f2bf(v[e]);
        }
        u16* dst = patches + (size_t)(b * 1296 + i * 36 + j) * 768 + c * 256 + p * 16;
        *(u16x8*)dst = lo;
        *(u16x8*)(dst + 8) = hi;
        return;
    }
    id -= 972;
    if (id < 576) {           // ---- conv_w cvt (already N x K layout)
        int i = id * 256 + threadIdx.x;
        f32x4 v = ((const f32x4*)conv_w)[i];
        union { u16 q[4]; u64 ll; } un;
        #pragma unroll
        for (int jj = 0; jj < 4; ++jj) un.q[jj] = f2bf(v[jj]);
        ((u64*)convw_bf)[i] = un.ll;
        return;
    }
    id -= 576;
    const float* src; u16* dst; int K, N;
    if (id < 576)       { src = wq; dst = wqkv_t;                 K = 768;  N = 768; }
    else if (id < 1152) { src = wk; dst = wqkv_t + 768 * 768;     K = 768;  N = 768;  id -= 576; }
    else if (id < 1728) { src = wv; dst = wqkv_t + 2 * 768 * 768; K = 768;  N = 768;  id -= 1152; }
    else if (id < 2304) { src = wo; dst = wo_t;                   K = 768;  N = 768;  id -= 1728; }
    else if (id < 4608) { src = w1; dst = w1_t;                   K = 768;  N = 3072; id -= 2304; }
    else                { src = w2; dst = w2_t;                   K = 3072; N = 768;  id -= 4608; }
    int nbx = N >> 5;
    int bx = id % nbx, by = id / nbx;
    int n0 = bx * 32, k0 = by * 32;
    int tx = threadIdx.x & 31, ty = threadIdx.x >> 5;   // 32 x 8
    #pragma unroll
    for (int i = 0; i < 32; i += 8)
        tile[ty + i][tx] = src[(size_t)(k0 + ty + i) * N + n0 + tx];
    __syncthreads();
    #pragma unroll
    for (int i = 0; i < 32; i += 8)
        dst[(size_t)(n0 + ty + i) * K + k0 + tx] = f2bf(tile[tx][ty + i]);
}

// ---------------- LayerNorm: f32 [5184][768] -> bf16 [5184][768] ----------------
__global__ __launch_bounds__(256) void ln_k(const float* __restrict__ x, const float* __restrict__ g,
                                            const float* __restrict__ bta, u16* __restrict__ out) {
    int row = blockIdx.x * 4 + (threadIdx.x >> 6);
    int l = threadIdx.x & 63;
    const float* xr = x + (size_t)row * 768;
    float v[12]; float s = 0.f, s2 = 0.f;
    #pragma unroll
    for (int i = 0; i < 12; ++i) { v[i] = xr[l + 64 * i]; s += v[i]; s2 += v[i] * v[i]; }
    #pragma unroll
    for (int off = 32; off; off >>= 1) { s += __shfl_xor(s, off); s2 += __shfl_xor(s2, off); }
    float mu = s * (1.f / 768.f);
    float var = s2 * (1.f / 768.f) - mu * mu;
    float rs = rsqrtf(var + 1e-5f);
    u16* orow = out + (size_t)row * 768;
    #pragma unroll
    for (int i = 0; i < 12; ++i) {
        int c = l + 64 * i;
        orow[c] = f2bf((v[i] - mu) * rs * g[c] + bta[c]);
    }
}

// ---------------- GEMM v5: C[M][N] = A[M][K] @ Bt[N][K]^T (+epilogue) ----------------
// BK=64 (128B LDS rows), piece^(row&7) swizzle, XCD-chunked bijective decode,
// double-buffered LDS with COUNTED vmcnt before s_barrier (prefetch stays in flight).
// EPI: 0 = +bias, f32 store        (patch embed -> tok)
//      1 = bf16 store, no bias; V-cols (>=1536) written TRANSPOSED into vt  (qkv)
//      2 = +bias, relu, bf16 store (mlp1 -> a1)
//      3 = +bias, +resid, f32 store(proj -> tok)
//      4 = +bias, +resid, f32 store TRANSPOSED to (B,E,T)   (mlp2 -> d_out)
template <int BN, int EPI>
__global__ __launch_bounds__(256) void gemm_k(const u16* __restrict__ A, const u16* __restrict__ Bt,
                                              const float* __restrict__ bias, const float* __restrict__ resid,
                                              u16* __restrict__ vtout,
                                              void* __restrict__ Cout, int K, int ldc, int nbx) {
    constexpr int M = 5184;
    constexpr int NF = BN / 32;
    __shared__ __align__(16) u16 lds[2][(128 + BN) * 64];
    const int tid = threadIdx.x;
    const int l = tid & 63, w = tid >> 6;
    const int lr = l & 15, lq = l >> 4;
    const int wm = w >> 1, wn = w & 1;

    const int total = nbx * 41;
    const int q = total >> 3, r = total & 7;
    const int x = blockIdx.x & 7;
    const int j = blockIdx.x >> 3;
    const int wrk = x * q + min(x, r) + j;
    const int by = wrk / nbx, bx = wrk - by * nbx;
    const int bm = by * 128;
    const int bn = bx * BN;

    f32x4 acc[4][NF];
    f32x4 zz = {0.f, 0.f, 0.f, 0.f};
    #pragma unroll
    for (int i = 0; i < 4; ++i)
        #pragma unroll
        for (int jj = 0; jj < NF; ++jj) acc[i][jj] = zz;

    const int nk = K >> 6;

    auto stage = [&](int buf, int kt) {
        u16* abase = &lds[buf][0];
        #pragma unroll
        for (int i = 0; i < 4; ++i) {
            int slot = tid + i * 256;
            int row = slot >> 3, piece = slot & 7;
            int sp = piece ^ (row & 7);
            const u16* src = A + (size_t)min(bm + row, M - 1) * K + kt * 64 + sp * 8;
            gll16(src, abase + ((tid & ~63) + i * 256) * 8);
        }
        u16* bbase = &lds[buf][128 * 64];
        #pragma unroll
        for (int i = 0; i < NF; ++i) {
            int slot = tid + i * 256;
            int row = slot >> 3, piece = slot & 7;
            int sp = piece ^ (row & 7);
            const u16* src = Bt + (size_t)(bn + row) * K + kt * 64 + sp * 8;
            gll16(src, bbase + ((tid & ~63) + i * 256) * 8);
        }
    };

    stage(0, 0);
    for (int kt = 0; kt < nk; ++kt) {
        const int cur = kt & 1;
        if (kt + 1 < nk) {
            stage(cur ^ 1, kt + 1);
            if constexpr (BN == 128) asm volatile("s_waitcnt vmcnt(8)\ns_barrier" ::: "memory");
            else                     asm volatile("s_waitcnt vmcnt(6)\ns_barrier" ::: "memory");
        } else {
            asm volatile("s_waitcnt vmcnt(0)\ns_barrier" ::: "memory");
        }
        bf16x8 af[4][2], bfr[NF][2];
        #pragma unroll
        for (int mi = 0; mi < 4; ++mi) {
            int row = wm * 64 + mi * 16 + lr;
            #pragma unroll
            for (int ks = 0; ks < 2; ++ks)
                af[mi][ks] = *(const bf16x8*)&lds[cur][row * 64 + (((lq + 4 * ks) ^ (row & 7)) << 3)];
        }
        #pragma unroll
        for (int ni = 0; ni < NF; ++ni) {
            int row = wn * (BN / 2) + ni * 16 + lr;
            #pragma unroll
            for (int ks = 0; ks < 2; ++ks)
                bfr[ni][ks] = *(const bf16x8*)&lds[cur][128 * 64 + row * 64 + (((lq + 4 * ks) ^ (row & 7)) << 3)];
        }
        #pragma unroll
        for (int mi = 0; mi < 4; ++mi)
            #pragma unroll
            for (int ni = 0; ni < NF; ++ni) {
                acc[mi][ni] = __builtin_amdgcn_mfma_f32_16x16x32_bf16(af[mi][0], bfr[ni][0], acc[mi][ni], 0, 0, 0);
                acc[mi][ni] = __builtin_amdgcn_mfma_f32_16x16x32_bf16(af[mi][1], bfr[ni][1], acc[mi][ni], 0, 0, 0);
            }
        asm volatile("s_barrier" ::: "memory");
    }

    #pragma unroll
    for (int mi = 0; mi < 4; ++mi) {
        #pragma unroll
        for (int ni = 0; ni < NF; ++ni) {
            int col = bn + wn * (BN / 2) + ni * 16 + lr;
            float bv = 0.f;
            if constexpr (EPI != 1) bv = bias[col];
            if constexpr (EPI == 1) {
                int m0 = bm + wm * 64 + mi * 16 + 4 * lq;
                if (m0 < M) {
                    if (col < 1536) {       // Q,K: row-major bf16 store
                        #pragma unroll
                        for (int rr = 0; rr < 4; ++rr)
                            ((u16*)Cout)[(size_t)(m0 + rr) * ldc + col] = f2bf(acc[mi][ni][rr]);
                    } else {                // V: transposed into vt[bh][d][t] (4 consecutive t)
                        int bb = m0 / 1296, t = m0 - bb * 1296;
                        int d = col - 1536;
                        int bh = bb * 12 + (d >> 6), dd = d & 63;
                        bf16x4 pv = __builtin_convertvector(acc[mi][ni], bf16x4);
                        *(bf16x4*)&vtout[(size_t)(bh * 64 + dd) * 1344 + t] = pv;
                    }
                }
            } else {
                #pragma unroll
                for (int rr = 0; rr < 4; ++rr) {
                    int m = bm + wm * 64 + mi * 16 + 4 * lq + rr;
                    if (m < M) {
                        float v = acc[mi][ni][rr] + bv;
                        if constexpr (EPI == 2) v = fmaxf(v, 0.f);
                        if constexpr (EPI == 3 || EPI == 4) v += resid[(size_t)m * ldc + col];
                        if constexpr (EPI == 0 || EPI == 3) {
                            ((float*)Cout)[(size_t)m * ldc + col] = v;
                        } else if constexpr (EPI == 4) {
                            int b = m / 1296, t = m - b * 1296;
                            ((float*)Cout)[(size_t)(b * 768 + col) * 1296 + t] = v;
                        } else {
                            ((u16*)Cout)[(size_t)m * ldc + col] = f2bf(v);
                        }
                    }
                }
            }
        }
    }
}

// ---------------- flash attention v5: swapped QK^T, merged S/L phases ----------------
// 528 blocks, XCD-affine (id%8 == bh%8). Wave-unit u: q0S=16u (u<40), q0L=16*(80-u).
// Per kt both tiles processed in ONE phase set: QK burst (S+L) -> straight-line softmax
// S+L (independent chains, ILP) -> P writes -> one wave_barrier -> PV burst -> barrier.
__global__ __launch_bounds__(256, 2) void attn_k(const u16* __restrict__ qkv, const u16* __restrict__ vt,
                                                 u16* __restrict__ ao) {
    const float SCALE = 0.03608439182435161f;   // 768^-0.5
    __shared__ __align__(16) u16 kv[2][2][4096];
    __shared__ __align__(16) u16 plds[4][2 * 16 * 72];
    const int tid = threadIdx.x;
    const int wid = tid >> 6, l = tid & 63;
    const int id = blockIdx.x;
    const int xr = id & 7, sl = id >> 3;
    const int g = sl / 11, bx = sl - g * 11;
    const int bh = g * 8 + xr;
    const int b = bh / 12, h = bh % 12;
    const int uu = bx * 4 + wid;
    const int u = min(uu, 40);
    const bool valid = (uu <= 40);
    const int lr = l & 15, lq = l >> 4;
    const int q0S = 16 * u, q0L = 16 * (80 - u);
    const bool hasS = valid && (u < 40);
    const int nktS = (u < 40) ? (((q0S + 15) >> 6) + 1) : 0;
    const int nktL = ((q0L + 15) >> 6) + 1;
    const int umin = min(bx * 4, 40);
    const int nktmax = ((16 * (80 - umin) + 15) >> 6) + 1;

    const u16* kbase = qkv + (size_t)(b * 1296) * 2304 + 768 + h * 64;
    const u16* vbase = vt + (size_t)bh * 64 * 1344;
    u16* plS = &plds[wid][0];
    u16* plL = &plds[wid][16 * 72];

    const u16* qpS = qkv + (size_t)(b * 1296 + q0S + lr) * 2304 + h * 64;
    const u16* qpL = qkv + (size_t)(b * 1296 + q0L + lr) * 2304 + h * 64;
    bf16x8 qS0 = *(const bf16x8*)(qpS + 8 * lq);
    bf16x8 qS1 = *(const bf16x8*)(qpS + 32 + 8 * lq);
    bf16x8 qL0 = *(const bf16x8*)(qpL + 8 * lq);
    bf16x8 qL1 = *(const bf16x8*)(qpL + 32 + 8 * lq);

    f32x4 zz = {0.f, 0.f, 0.f, 0.f};
    const float NEG = -__builtin_inff();
    f32x4 oS[4], oL[4];
    float mS = NEG, mL = NEG, lS = 0.f, lL = 0.f;
    #pragma unroll
    for (int i = 0; i < 4; ++i) { oS[i] = zz; oL[i] = zz; }

    auto stage = [&](int buf, int kt) {
        const int k0 = kt * 64;
        #pragma unroll
        for (int i = 0; i < 2; ++i) {
            int slot = tid + i * 256;
            int row = slot >> 3, piece = slot & 7;
            int sp = piece ^ (row & 7);
            int tc = min(k0 + row, 1295);
            gll16(kbase + (size_t)tc * 2304 + sp * 8,
                  &kv[buf][0][((tid & 0xFFFFFFC0) + i * 256) * 8]);
        }
        #pragma unroll
        for (int i = 0; i < 2; ++i) {
            int slot = tid + i * 256;
            int row = slot >> 3, piece = slot & 7;
            int sp = piece ^ (row & 7);
            gll16(vbase + (size_t)row * 1344 + k0 + sp * 8,
                  &kv[buf][1][((tid & 0xFFFFFFC0) + i * 256) * 8]);
        }
    };

    bf16x8 kb[4][2], vb[4][2];

    stage(0, 0);
    for (int kt = 0; kt < nktmax; ++kt) {
        const int cur = kt & 1;
        const int k0 = kt * 64;
        __syncthreads();
        if (kt + 1 < nktmax) stage(cur ^ 1, kt + 1);
        #pragma unroll
        for (int nt = 0; nt < 4; ++nt) {
            int krow = nt * 16 + lr;
            kb[nt][0] = *(const bf16x8*)&kv[cur][0][krow * 64 + ((lq ^ (krow & 7)) << 3)];
            kb[nt][1] = *(const bf16x8*)&kv[cur][0][krow * 64 + (((lq + 4) ^ (krow & 7)) << 3)];
        }
        #pragma unroll
        for (int dt = 0; dt < 4; ++dt) {
            int vrow = dt * 16 + lr;
            vb[dt][0] = *(const bf16x8*)&kv[cur][1][vrow * 64 + ((lq ^ (vrow & 7)) << 3)];
            vb[dt][1] = *(const bf16x8*)&kv[cur][1][vrow * 64 + (((lq + 4) ^ (vrow & 7)) << 3)];
        }
        const bool doS = valid && (kt < nktS);
        const bool doL = valid && (kt < nktL);
        if (doS) {                 // both tiles (nktS <= nktL)
            const int qrS = q0S + lr, qrL = q0L + lr;
            f32x4 sS[4], sL[4];
            __builtin_amdgcn_s_setprio(1);
            #pragma unroll
            for (int nt = 0; nt < 4; ++nt) {
                f32x4 a = zz;
                a = __builtin_amdgcn_mfma_f32_16x16x32_bf16(kb[nt][0], qS0, a, 0, 0, 0);
                a = __builtin_amdgcn_mfma_f32_16x16x32_bf16(kb[nt][1], qS1, a, 0, 0, 0);
                sS[nt] = a;
            }
            #pragma unroll
            for (int nt = 0; nt < 4; ++nt) {
                f32x4 a = zz;
                a = __builtin_amdgcn_mfma_f32_16x16x32_bf16(kb[nt][0], qL0, a, 0, 0, 0);
                a = __builtin_amdgcn_mfma_f32_16x16x32_bf16(kb[nt][1], qL1, a, 0, 0, 0);
                sL[nt] = a;
            }
            __builtin_amdgcn_s_setprio(0);
            float mntS[4], mntL[4];
            #pragma unroll
            for (int nt = 0; nt < 4; ++nt) {
                #pragma unroll
                for (int r = 0; r < 4; ++r) {
                    int k = k0 + nt * 16 + 4 * lq + r;
                    sS[nt][r] = (k <= qrS) ? sS[nt][r] : NEG;
                    sL[nt][r] = (k <= qrL) ? sL[nt][r] : NEG;
                }
                mntS[nt] = fmaxf(fmaxf(sS[nt][0], sS[nt][1]), fmaxf(sS[nt][2], sS[nt][3]));
                mntL[nt] = fmaxf(fmaxf(sL[nt][0], sL[nt][1]), fmaxf(sL[nt][2], sL[nt][3]));
            }
            float mxS = fmaxf(fmaxf(mntS[0], mntS[1]), fmaxf(mntS[2], mntS[3]));
            float mxL = fmaxf(fmaxf(mntL[0], mntL[1]), fmaxf(mntL[2], mntL[3]));
            mxS = fmaxf(mxS, __shfl_xor(mxS, 16));
            mxL = fmaxf(mxL, __shfl_xor(mxL, 16));
            mxS = fmaxf(mxS, __shfl_xor(mxS, 32));
            mxL = fmaxf(mxL, __shfl_xor(mxL, 32));
            float nmS = fmaxf(mS, mxS), nmL = fmaxf(mL, mxL);
            float aS = __expf(SCALE * (mS - nmS)), aL = __expf(SCALE * (mL - nmL));
            mS = nmS; mL = nmL;
            float nbS = -SCALE * nmS, nbL = -SCALE * nmL;
            float tS = 0.f, tL = 0.f;
            #pragma unroll
            for (int nt = 0; nt < 4; ++nt) {
                #pragma unroll
                for (int r = 0; r < 4; ++r) {
                    sS[nt][r] = __expf(fmaf(sS[nt][r], SCALE, nbS));
                    sL[nt][r] = __expf(fmaf(sL[nt][r], SCALE, nbL));
                }
                tS += (sS[nt][0] + sS[nt][1]) + (sS[nt][2] + sS[nt][3]);
                tL += (sL[nt][0] + sL[nt][1]) + (sL[nt][2] + sL[nt][3]);
            }
            tS += __shfl_xor(tS, 16); tL += __shfl_xor(tL, 16);
            tS += __shfl_xor(tS, 32); tL += __shfl_xor(tL, 32);
            lS = lS * aS + tS;
            lL = lL * aL + tL;
            #pragma unroll
            for (int dt = 0; dt < 4; ++dt) { oS[dt] *= aS; oL[dt] *= aL; }
            #pragma unroll
            for (int nt = 0; nt < 4; ++nt) {
                *(bf16x4*)&plS[lr * 72 + nt * 16 + 4 * lq] = __builtin_convertvector(sS[nt], bf16x4);
                *(bf16x4*)&plL[lr * 72 + nt * 16 + 4 * lq] = __builtin_convertvector(sL[nt], bf16x4);
            }
            __builtin_amdgcn_wave_barrier();
            bf16x8 paS0 = *(const bf16x8*)&plS[lr * 72 + 8 * lq];
            bf16x8 paS1 = *(const bf16x8*)&plS[lr * 72 + 32 + 8 * lq];
            bf16x8 paL0 = *(const bf16x8*)&plL[lr * 72 + 8 * lq];
            bf16x8 paL1 = *(const bf16x8*)&plL[lr * 72 + 32 + 8 * lq];
            __builtin_amdgcn_s_setprio(1);
            #pragma unroll
            for (int dt = 0; dt < 4; ++dt) {
                oS[dt] = __builtin_amdgcn_mfma_f32_16x16x32_bf16(vb[dt][0], paS0, oS[dt], 0, 0, 0);
                oS[dt] = __builtin_amdgcn_mfma_f32_16x16x32_bf16(vb[dt][1], paS1, oS[dt], 0, 0, 0);
                oL[dt] = __builtin_amdgcn_mfma_f32_16x16x32_bf16(vb[dt][0], paL0, oL[dt], 0, 0, 0);
                oL[dt] = __builtin_amdgcn_mfma_f32_16x16x32_bf16(vb[dt][1], paL1, oL[dt], 0, 0, 0);
            }
            __builtin_amdgcn_s_setprio(0);
            __builtin_amdgcn_wave_barrier();
        } else if (doL) {          // L only
            const int qrL = q0L + lr;
            f32x4 sL[4];
            __builtin_amdgcn_s_setprio(1);
            #pragma unroll
            for (int nt = 0; nt < 4; ++nt) {
                f32x4 a = zz;
                a = __builtin_amdgcn_mfma_f32_16x16x32_bf16(kb[nt][0], qL0, a, 0, 0, 0);
                a = __builtin_amdgcn_mfma_f32_16x16x32_bf16(kb[nt][1], qL1, a, 0, 0, 0);
                sL[nt] = a;
            }
            __builtin_amdgcn_s_setprio(0);
            float mntL[4];
            #pragma unroll
            for (int nt = 0; nt < 4; ++nt) {
                #pragma unroll
                for (int r = 0; r < 4; ++r) {
                    int k = k0 + nt * 16 + 4 * lq + r;
                    sL[nt][r] = (k <= qrL) ? sL[nt][r] : NEG;
                }
                mntL[nt] = fmaxf(fmaxf(sL[nt][0], sL[nt][1]), fmaxf(sL[nt][2], sL[nt][3]));
            }
            float mxL = fmaxf(fmaxf(mntL[0], mntL[1]), fmaxf(mntL[2], mntL[3]));
            mxL = fmaxf(mxL, __shfl_xor(mxL, 16));
            mxL = fmaxf(mxL, __shfl_xor(mxL, 32));
            float nmL = fmaxf(mL, mxL);
            float aL = __expf(SCALE * (mL - nmL));
            mL = nmL;
            float nbL = -SCALE * nmL;
            float tL = 0.f;
            #pragma unroll
            for (int nt = 0; nt < 4; ++nt) {
                #pragma unroll
                for (int r = 0; r < 4; ++r)
                    sL[nt][r] = __expf(fmaf(sL[nt][r], SCALE, nbL));
                tL += (sL[nt][0] + sL[nt][1]) + (sL[nt][2] + sL[nt][3]);
            }
            tL += __shfl_xor(tL, 16);
            tL += __shfl_xor(tL, 32);
            lL = lL * aL + tL;
            #pragma unroll
            for (int dt = 0; dt < 4; ++dt) oL[dt] *= aL;
            #pragma unroll
            for (int nt = 0; nt < 4; ++nt)
                *(bf16x4*)&plL[lr * 72 + nt * 16 + 4 * lq] = __builtin_convertvector(sL[nt], bf16x4);
            __builtin_amdgcn_wave_barrier();
            bf16x8 paL0 = *(const bf16x8*)&plL[lr * 72 + 8 * lq];
            bf16x8 paL1 = *(const bf16x8*)&plL[lr * 72 + 32 + 8 * lq];
            __builtin_amdgcn_s_setprio(1);
            #pragma unroll
            for (int dt = 0; dt < 4; ++dt) {
                oL[dt] = __builtin_amdgcn_mfma_f32_16x16x32_bf16(vb[dt][0], paL0, oL[dt], 0, 0, 0);
                oL[dt] = __builtin_amdgcn_mfma_f32_16x16x32_bf16(vb[dt][1], paL1, oL[dt], 0, 0, 0);
            }
            __builtin_amdgcn_s_setprio(0);
            __builtin_amdgcn_wave_barrier();
        }
    }

    if (valid) {
        if (hasS) {
            float inv = 1.f / lS;
            u16* aoS = ao + (size_t)(b * 1296 + q0S + lr) * 768 + h * 64 + 4 * lq;
            #pragma unroll
            for (int dt = 0; dt < 4; ++dt) {
                f32x4 ov = oS[dt] * inv;
                *(bf16x4*)(aoS + dt * 16) = __builtin_convertvector(ov, bf16x4);
            }
        }
        float invL = 1.f / lL;
        u16* aoL = ao + (size_t)(b * 1296 + q0L + lr) * 768 + h * 64 + 4 * lq;
        #pragma unroll
        for (int dt = 0; dt < 4; ++dt) {
            f32x4 ov = oL[dt] * invL;
            *(bf16x4*)(aoL + dt * 16) = __builtin_convertvector(ov, bf16x4);
        }
    }
}

extern "C" void kernel_launch(void* const* d_in, const int* in_sizes, int n_in,
                              void* d_out, int out_size, void* d_ws, size_t ws_size,
                              hipStream_t stream) {
    const float* x      = (const float*)d_in[0];
    const float* conv_w = (const float*)d_in[1];
    const float* conv_b = (const float*)d_in[2];
    const float* wq     = (const float*)d_in[3];
    const float* wk     = (const float*)d_in[4];
    const float* wv     = (const float*)d_in[5];
    const float* wo     = (const float*)d_in[6];
    const float* bo     = (const float*)d_in[7];
    const float* w1     = (const float*)d_in[8];
    const float* b1     = (const float*)d_in[9];
    const float* w2     = (const float*)d_in[10];
    const float* b2     = (const float*)d_in[11];
    const float* ln1g   = (const float*)d_in[12];
    const float* ln1b   = (const float*)d_in[13];
    const float* ln2g   = (const float*)d_in[14];
    const float* ln2b   = (const float*)d_in[15];

    char* ws = (char*)d_ws;
    size_t off = 0;
    auto alloc = [&](size_t bytes) { char* p = ws + off; off = (off + bytes + 255) & ~(size_t)255; return p; };
    u16*   convw_bf = (u16*)alloc((size_t)768 * 768 * 2);
    u16*   wqkv_t   = (u16*)alloc((size_t)2304 * 768 * 2);
    u16*   wo_t     = (u16*)alloc((size_t)768 * 768 * 2);
    u16*   w1_t     = (u16*)alloc((size_t)3072 * 768 * 2);
    u16*   w2_t     = (u16*)alloc((size_t)768 * 3072 * 2);
    float* tok      = (float*)alloc((size_t)5184 * 768 * 4);
    u16*   hbuf     = (u16*)alloc((size_t)5184 * 768 * 2);
    u16*   apao     = (u16*)alloc((size_t)5184 * 768 * 2);   // patches, later attention output
    size_t qkv_bytes = ((size_t)5184 * 2304 * 2 + 255) & ~(size_t)255;
    size_t vt_bytes  = (size_t)48 * 64 * 1344 * 2;
    size_t a1_bytes  = (size_t)5184 * 3072 * 2;
    size_t big_bytes = qkv_bytes + vt_bytes;
    if (a1_bytes > big_bytes) big_bytes = a1_bytes;
    char* big = alloc(big_bytes);
    u16* qkvb = (u16*)big;
    u16* vtb  = (u16*)(big + qkv_bytes);
    u16* a1   = (u16*)big;   // overlays qkv+vt (dead after attention)

    // 1. fused prep: patch gather + conv cvt + all weight transposes (one launch)
    prep_k<<<8460, 256, 0, stream>>>(x, conv_w, wq, wk, wv, wo, w1, w2,
                                     apao, convw_bf, wqkv_t, wo_t, w1_t, w2_t);
    // 2. patch-embed GEMM -> tok (f32)
    gemm_k<64, 0><<<12 * 41, 256, 0, stream>>>(apao, convw_bf, conv_b, nullptr, nullptr, tok, 768, 768, 12);
    // 3. LN1 -> h (bf16)
    ln_k<<<1296, 256, 0, stream>>>(tok, ln1g, ln1b, hbuf);
    // 4. fused QKV GEMM -> qkv (Q,K) + vt (V transposed, fused)
    gemm_k<128, 1><<<18 * 41, 256, 0, stream>>>(hbuf, wqkv_t, nullptr, nullptr, vtb, qkvb, 768, 2304, 18);
    // 5. attention -> ao (reuses patch buffer)
    attn_k<<<528, 256, 0, stream>>>(qkvb, vtb, apao);
    // 6. output proj + residual -> tok
    gemm_k<64, 3><<<12 * 41, 256, 0, stream>>>(apao, wo_t, bo, tok, nullptr, tok, 768, 768, 12);
    // 7. LN2 -> h
    ln_k<<<1296, 256, 0, stream>>>(tok, ln2g, ln2b, hbuf);
    // 8. MLP1 (relu) -> a1
    gemm_k<128, 2><<<24 * 41, 256, 0, stream>>>(hbuf, w1_t, b1, nullptr, nullptr, a1, 768, 3072, 24);
    // 9. MLP2 + residual, store transposed (B,E,36,36) -> d_out (f32)
    gemm_k<64, 4><<<12 * 41, 256, 0, stream>>>(a1, w2_t, b2, tok, nullptr, d_out, 3072, 768, 12);
}